// Round 1
// baseline (159.369 us; speedup 1.0000x reference)
//
#include <hip/hip_runtime.h>
#include <math.h>

#define N_KCS 5000
#define TT    100
#define BB    512

__device__ __forceinline__ float sigmoidf(float x) {
    return 1.0f / (1.0f + expf(-x));
}

// One workgroup per batch row. State row lives in LDS (20 KB).
// Lane 0 runs the sequential T-step scan; all 256 threads do the
// state init and the coalesced float4 writeback.
__global__ __launch_bounds__(256) void bkt_kernel(
    const int*   __restrict__ prev_kc,
    const int*   __restrict__ curr_kc,
    const int*   __restrict__ prev_corr,
    const float* __restrict__ logits,     // (N_KCS, 5) row-major
    float*       __restrict__ probs_out,  // (B, T)
    float*       __restrict__ state_out)  // (B, N_KCS)
{
    __shared__ float state[N_KCS];
    const int b   = blockIdx.x;
    const int tid = threadIdx.x;

    // --- init state row: sigmoid(logits[:,4]) ---
    for (int k = tid; k < N_KCS; k += 256) {
        state[k] = sigmoidf(logits[k * 5 + 4]);
    }
    __syncthreads();

    if (tid == 0) {
        const int base = b * TT;

        // t = 0
        {
            int ck0   = curr_kc[base];
            float cp2 = sigmoidf(logits[ck0 * 5 + 2]);
            float cp3 = sigmoidf(logits[ck0 * 5 + 3]);
            float cs0 = state[ck0];
            probs_out[base] = cp2 * (1.0f - cs0) + cp3 * cs0;
        }

        // software-pipelined prefetch of step t=1
        int   pk = prev_kc[base + 1];
        int   ck = curr_kc[base + 1];
        int   c  = prev_corr[base + 1];
        float l0 = logits[pk * 5 + 0];
        float l1 = logits[pk * 5 + 1];
        float l2 = logits[pk * 5 + 2];
        float l3 = logits[pk * 5 + 3];
        float m2 = logits[ck * 5 + 2];
        float m3 = logits[ck * 5 + 3];

        for (int t = 1; t < TT; ++t) {
            // issue both state reads up front (s_ck misses only this step's
            // write, patched with the ck==pk select below)
            float s_pk = state[pk];
            float s_ck = state[ck];

            // prefetch next iteration (global loads — independent of LDS chain)
            int pk_n = 0, ck_n = 0, c_n = 0;
            float l0n = 0.f, l1n = 0.f, l2n = 0.f, l3n = 0.f, m2n = 0.f, m3n = 0.f;
            if (t + 1 < TT) {
                pk_n = prev_kc[base + t + 1];
                ck_n = curr_kc[base + t + 1];
                c_n  = prev_corr[base + t + 1];
                l0n = logits[pk_n * 5 + 0];
                l1n = logits[pk_n * 5 + 1];
                l2n = logits[pk_n * 5 + 2];
                l3n = logits[pk_n * 5 + 3];
                m2n = logits[ck_n * 5 + 2];
                m3n = logits[ck_n * 5 + 3];
            }

            // off-chain ALU: sigmoids from prefetched logits
            float pp0 = sigmoidf(l0);
            float pp1 = sigmoidf(l1);
            float pp2 = sigmoidf(l2);
            float pp3 = sigmoidf(l3);
            float cp2 = sigmoidf(m2);
            float cp3 = sigmoidf(m3);

            // p_out = pch^c * (1-pch)^(1-c) with c in {0,1}  ==  select
            float po0 = c ? pp2 : (1.0f - pp2);
            float po1 = c ? pp3 : (1.0f - pp3);

            float num  = po1 * s_pk;
            float filt = num / (po0 * (1.0f - s_pk) + num);
            float predictive = pp0 * (1.0f - filt) + (1.0f - pp1) * filt;

            state[pk] = predictive;

            float cs = (ck == pk) ? predictive : s_ck;
            probs_out[base + t] = cp2 * (1.0f - cs) + cp3 * cs;

            // rotate pipeline registers
            pk = pk_n; ck = ck_n; c = c_n;
            l0 = l0n; l1 = l1n; l2 = l2n; l3 = l3n; m2 = m2n; m3 = m3n;
        }
    }
    __syncthreads();

    // --- coalesced float4 writeback of final state ---
    float* out_row = state_out + (size_t)b * N_KCS;
    for (int k = tid * 4; k < N_KCS; k += 256 * 4) {
        float4 v = *(const float4*)&state[k];
        *(float4*)&out_row[k] = v;
    }
}

extern "C" void kernel_launch(void* const* d_in, const int* in_sizes, int n_in,
                              void* d_out, int out_size, void* d_ws, size_t ws_size,
                              hipStream_t stream) {
    const int*   prev_kc   = (const int*)d_in[0];
    const int*   curr_kc   = (const int*)d_in[1];
    const int*   prev_corr = (const int*)d_in[2];
    const float* logits    = (const float*)d_in[3];

    float* out     = (float*)d_out;
    float* probs   = out;                 // B*T floats
    float* state_f = out + BB * TT;       // B*N_KCS floats

    bkt_kernel<<<BB, 256, 0, stream>>>(prev_kc, curr_kc, prev_corr, logits,
                                       probs, state_f);
}

// Round 2
// 76.458 us; speedup vs baseline: 2.0844x; 2.0844x over previous
//
#include <hip/hip_runtime.h>
#include <math.h>

#define N_KCS 5000
#define TT    100
#define BB    512

__device__ __forceinline__ float sigmoidf(float x) {
    return 1.0f / (1.0f + expf(-x));
}

// One workgroup per batch row. The sequential scan is replaced by parallel
// per-kc chain resolution: steps touching distinct kcs are independent; with
// T=100 draws from 5000 kcs, chains have expected length ~1. Each chain is
// walked with arithmetic identical to the reference step (bit-exact vs R1).
__global__ __launch_bounds__(256) void bkt_kernel(
    const int*   __restrict__ prev_kc,
    const int*   __restrict__ curr_kc,
    const int*   __restrict__ prev_corr,
    const float* __restrict__ logits,     // (N_KCS, 5) row-major
    float*       __restrict__ probs_out,  // (B, T)
    float*       __restrict__ state_out)  // (B, N_KCS)
{
    __shared__ float state[N_KCS];                       // 20 KB
    __shared__ int   pk_s[TT], ck_s[TT], nxt_s[TT];
    __shared__ float po0_s[TT], po1_s[TT], pp0_s[TT], pp1_s[TT];
    __shared__ float cp2_s[TT], cp3_s[TT], pred_s[TT];

    const int b    = blockIdx.x;
    const int tid  = threadIdx.x;
    const int base = b * TT;

    // --- stage indices + init state row (pristine) ---
    if (tid < TT) {
        pk_s[tid] = prev_kc[base + tid];
        ck_s[tid] = curr_kc[base + tid];
    }
    for (int k = tid; k < N_KCS; k += 256) {
        state[k] = sigmoidf(logits[k * 5 + 4]);
    }
    __syncthreads();

    const int  t   = tid;
    const bool act = (t >= 1 && t < TT);
    int  lst  = -1;     // last t' <= t with pk[t'] == ck[t]   (for cs read)
    bool head = true;   // no t' <  t with pk[t'] == pk[t]     (chain head)

    if (act) {
        const int mypk = pk_s[t];
        const int myck = ck_s[t];
        const int c    = prev_corr[base + t];

        // state-independent per-step constants (parallel across lanes)
        float pp2 = sigmoidf(logits[mypk * 5 + 2]);
        float pp3 = sigmoidf(logits[mypk * 5 + 3]);
        pp0_s[t] = sigmoidf(logits[mypk * 5 + 0]);
        pp1_s[t] = sigmoidf(logits[mypk * 5 + 1]);
        cp2_s[t] = sigmoidf(logits[myck * 5 + 2]);
        cp3_s[t] = sigmoidf(logits[myck * 5 + 3]);
        // pch^c * (1-pch)^(1-c) with c in {0,1} == select (bit-exact in R1)
        po0_s[t] = c ? pp2 : (1.0f - pp2);
        po1_s[t] = c ? pp3 : (1.0f - pp3);

        // parallel linkage: scan all step indices (LDS broadcast reads)
        int nxt = -1;
        for (int tp = 1; tp < TT; ++tp) {
            int p = pk_s[tp];
            if (p == mypk) {
                if (tp < t)                    head = false;
                else if (tp > t && nxt == -1)  nxt  = tp;
            }
            if (p == myck && tp <= t) lst = tp;   // increasing tp -> keeps max
        }
        nxt_s[t] = nxt;
    }

    // t = 0 prob: state untouched, cs0 = init(ck0)
    if (t == 0) {
        int   ck0 = ck_s[0];
        float cp2 = sigmoidf(logits[ck0 * 5 + 2]);
        float cp3 = sigmoidf(logits[ck0 * 5 + 3]);
        float cs0 = state[ck0];
        probs_out[base] = cp2 * (1.0f - cs0) + cp3 * cs0;
    }
    __syncthreads();

    // --- chain walk: head lanes evaluate their kc-chain sequentially ---
    // (expected length ~1; arithmetic identical to the reference step)
    if (act && head) {
        float s = state[pk_s[t]];   // pristine init for this kc
        int   u = t;
        while (u != -1) {
            float num        = po1_s[u] * s;
            float filt       = num / (po0_s[u] * (1.0f - s) + num);
            float predictive = pp0_s[u] * (1.0f - filt) + (1.0f - pp1_s[u]) * filt;
            pred_s[u] = predictive;
            s = predictive;
            u = nxt_s[u];
        }
    }
    __syncthreads();

    // --- probs: cs = pred at last write <= t, else pristine init ---
    if (act) {
        float cs = (lst == -1) ? state[ck_s[t]] : pred_s[lst];
        probs_out[base + t] = cp2_s[t] * (1.0f - cs) + cp3_s[t] * cs;
    }
    __syncthreads();   // keep pristine state reads ordered before overrides

    // --- tail overrides into state row ---
    if (act && nxt_s[t] == -1) {
        state[pk_s[t]] = pred_s[t];
    }
    __syncthreads();

    // --- coalesced float4 writeback of final state ---
    float* out_row = state_out + (size_t)b * N_KCS;
    for (int k = tid * 4; k < N_KCS; k += 256 * 4) {
        *(float4*)&out_row[k] = *(const float4*)&state[k];
    }
}

extern "C" void kernel_launch(void* const* d_in, const int* in_sizes, int n_in,
                              void* d_out, int out_size, void* d_ws, size_t ws_size,
                              hipStream_t stream) {
    const int*   prev_kc   = (const int*)d_in[0];
    const int*   curr_kc   = (const int*)d_in[1];
    const int*   prev_corr = (const int*)d_in[2];
    const float* logits    = (const float*)d_in[3];

    float* out     = (float*)d_out;
    float* probs   = out;                 // B*T floats
    float* state_f = out + BB * TT;       // B*N_KCS floats

    bkt_kernel<<<BB, 256, 0, stream>>>(prev_kc, curr_kc, prev_corr, logits,
                                       probs, state_f);
}

// Round 3
// 75.679 us; speedup vs baseline: 2.1059x; 1.0103x over previous
//
#include <hip/hip_runtime.h>
#include <math.h>

#define N_KCS 5000
#define TT    100
#define BB    512

__device__ __forceinline__ float sigmoidf(float x) {
    return 1.0f / (1.0f + expf(-x));
}

// --- Kernel A: precompute probs_tbl = sigmoid(logits) (25000 floats, 100 KB)
// and packed contiguous init_tbl = probs_tbl[:,4] (5000 floats, 20 KB).
// Same sigmoidf on same inputs as before -> bit-identical values.
__global__ __launch_bounds__(256) void sigmoid_tbl_kernel(
    const float* __restrict__ logits,
    float*       __restrict__ tbl,       // N_KCS*5
    float*       __restrict__ init_tbl)  // N_KCS
{
    int i = blockIdx.x * 256 + threadIdx.x;
    if (i < N_KCS * 5) {
        float s = sigmoidf(logits[i]);
        tbl[i] = s;
        if (i % 5 == 4) init_tbl[i / 5] = s;
    }
}

// --- Kernel B: one workgroup per batch row. Parallel per-kc chain resolution
// (chains over same kc have expected length ~1 for T=100 draws of 5000 kcs).
// All sigmoids come from the precomputed table; zero expf here.
__global__ __launch_bounds__(256) void bkt_kernel(
    const int*   __restrict__ prev_kc,
    const int*   __restrict__ curr_kc,
    const int*   __restrict__ prev_corr,
    const float* __restrict__ tbl,        // (N_KCS,5) sigmoided
    const float* __restrict__ init_tbl,   // (N_KCS,) packed column 4
    float*       __restrict__ probs_out,  // (B, T)
    float*       __restrict__ state_out)  // (B, N_KCS)
{
    __shared__ float state[N_KCS];                       // 20 KB
    __shared__ int   pk_s[TT], ck_s[TT], nxt_s[TT];
    __shared__ float po0_s[TT], po1_s[TT], pp0_s[TT], pp1_s[TT];
    __shared__ float cp2_s[TT], cp3_s[TT], pred_s[TT];

    const int b    = blockIdx.x;
    const int tid  = threadIdx.x;
    const int base = b * TT;

    // stage indices + init state row by coalesced float4 copy (L2-resident)
    if (tid < TT) {
        pk_s[tid] = prev_kc[base + tid];
        ck_s[tid] = curr_kc[base + tid];
    }
    for (int k = tid * 4; k < N_KCS; k += 256 * 4) {   // N_KCS % 4 == 0
        *(float4*)&state[k] = *(const float4*)&init_tbl[k];
    }
    __syncthreads();

    const int  t   = tid;
    const bool act = (t >= 1 && t < TT);
    int  lst  = -1;     // last t' <= t with pk[t'] == ck[t]   (for cs read)
    bool head = true;   // no t' <  t with pk[t'] == pk[t]     (chain head)

    if (act) {
        const int mypk = pk_s[t];
        const int myck = ck_s[t];
        const int c    = prev_corr[base + t];

        // state-independent per-step constants: table gathers (L2 hits)
        float pp2 = tbl[mypk * 5 + 2];
        float pp3 = tbl[mypk * 5 + 3];
        pp0_s[t] = tbl[mypk * 5 + 0];
        pp1_s[t] = tbl[mypk * 5 + 1];
        cp2_s[t] = tbl[myck * 5 + 2];
        cp3_s[t] = tbl[myck * 5 + 3];
        // pch^c * (1-pch)^(1-c) with c in {0,1} == select (bit-exact)
        po0_s[t] = c ? pp2 : (1.0f - pp2);
        po1_s[t] = c ? pp3 : (1.0f - pp3);

        // parallel linkage: scan all step indices (LDS broadcast reads)
        int nxt = -1;
        for (int tp = 1; tp < TT; ++tp) {
            int p = pk_s[tp];
            if (p == mypk) {
                if (tp < t)                    head = false;
                else if (tp > t && nxt == -1)  nxt  = tp;
            }
            if (p == myck && tp <= t) lst = tp;   // increasing tp -> keeps max
        }
        nxt_s[t] = nxt;
    }

    // t = 0 prob: state untouched, cs0 = init(ck0)
    if (t == 0) {
        int   ck0 = ck_s[0];
        float cs0 = state[ck0];
        probs_out[base] = tbl[ck0 * 5 + 2] * (1.0f - cs0) + tbl[ck0 * 5 + 3] * cs0;
    }
    __syncthreads();

    // chain walk: head lanes evaluate their kc-chain sequentially
    // (arithmetic identical to the reference scan step)
    if (act && head) {
        float s = state[pk_s[t]];   // pristine init for this kc
        int   u = t;
        while (u != -1) {
            float num        = po1_s[u] * s;
            float filt       = num / (po0_s[u] * (1.0f - s) + num);
            float predictive = pp0_s[u] * (1.0f - filt) + (1.0f - pp1_s[u]) * filt;
            pred_s[u] = predictive;
            s = predictive;
            u = nxt_s[u];
        }
    }
    __syncthreads();

    // probs: cs = pred at last write <= t, else pristine init
    if (act) {
        float cs = (lst == -1) ? state[ck_s[t]] : pred_s[lst];
        probs_out[base + t] = cp2_s[t] * (1.0f - cs) + cp3_s[t] * cs;
    }
    __syncthreads();   // keep pristine state reads ordered before overrides

    // tail overrides into state row
    if (act && nxt_s[t] == -1) {
        state[pk_s[t]] = pred_s[t];
    }
    __syncthreads();

    // coalesced float4 writeback of final state
    float* out_row = state_out + (size_t)b * N_KCS;
    for (int k = tid * 4; k < N_KCS; k += 256 * 4) {
        *(float4*)&out_row[k] = *(const float4*)&state[k];
    }
}

extern "C" void kernel_launch(void* const* d_in, const int* in_sizes, int n_in,
                              void* d_out, int out_size, void* d_ws, size_t ws_size,
                              hipStream_t stream) {
    const int*   prev_kc   = (const int*)d_in[0];
    const int*   curr_kc   = (const int*)d_in[1];
    const int*   prev_corr = (const int*)d_in[2];
    const float* logits    = (const float*)d_in[3];

    float* tbl      = (float*)d_ws;            // 25000 floats
    float* init_tbl = tbl + 25024;             // 5000 floats (16B-aligned)

    float* out     = (float*)d_out;
    float* probs   = out;                 // B*T floats
    float* state_f = out + BB * TT;       // B*N_KCS floats

    sigmoid_tbl_kernel<<<(N_KCS * 5 + 255) / 256, 256, 0, stream>>>(
        logits, tbl, init_tbl);
    bkt_kernel<<<BB, 256, 0, stream>>>(prev_kc, curr_kc, prev_corr,
                                       tbl, init_tbl, probs, state_f);
}